// Round 8
// baseline (217.130 us; speedup 1.0000x reference)
//
#include <hip/hip_runtime.h>

// BagOfWords: input [1024, 512] int32 tokens in [0, 50257).
// Output [1024, 50256] float32: per-row histogram, vocab bin 0 dropped.
//
// R11: hipMemsetAsync zero + sparse winner kernel. Model discriminator.
//
// Ledger: six structurally independent kernels (R0 fused / R1 atomics /
// R3 scatter / R5 mask / R6 wide / R10 persistent) all land 195-201 total.
// Two models fit: (A) our kernel ~72 us, stuck at 2.9 TB/s for unknown
// structural reasons; (B) the timed reset contains TWO poison fills
// (823 MB @ 123 us + 205.8 MB d_out @ ~31 us) and our kernel is ~36 us,
// i.e. already within ~15% of the 30.7 us write floor. Model A requires
// R3's pure streaming zero kernel to have run at 2.6 TB/s while rocclr's
// structurally identical fill hits 6.7 TB/s on the same buffer in the same
// window (R3-R5 arithmetic: Z+S+launch-K = 11.2 us) -- implausible but not
// yet excluded.
//
// This round swaps our zero phase for the literal rocclr fill kernel via
// hipMemsetAsync (stream-ordered, graph-capturable -- the harness reset
// itself uses it; memset 0 == 0.0f bitwise), followed by R3's verified
// sparse winner kernel (~506K nonzero bins; stores hit the MALL-dirty
// zero lines the memset just wrote, so no cold-line penalty).
//   Model B -> neutral (192-200): kernel was at roofline; declare next round.
//   Model A -> win (176-186): rocclr fill structure beats ours; iterate.

#define BATCH 1024
#define SEQ 512
#define VOCAB 50257
#define OUT_COLS (VOCAB - 1)   // 50256
#define CHUNK 4096
#define NCHUNK 13
#define BLOCK 256

// LDS-only barrier: waits ds ops (lgkmcnt) but does NOT drain global stores.
#define LDS_BAR()                                              \
    do {                                                       \
        asm volatile("s_waitcnt lgkmcnt(0)" ::: "memory");     \
        __builtin_amdgcn_s_barrier();                          \
        asm volatile("" ::: "memory");                         \
    } while (0)

__global__ __launch_bounds__(BLOCK) void bow_sparse_kernel(
    const int* __restrict__ tokens, float* __restrict__ out) {
    __shared__ unsigned int hist[CHUNK];  // 16 KB

    const int t = threadIdx.x;
    const int b = blockIdx.x;  // one block per row

    // Zero the 4096-bin chunk histogram once.
    const uint4 z4 = make_uint4(0u, 0u, 0u, 0u);
    #pragma unroll
    for (int k = 0; k < 4; ++k)
        *(uint4*)&hist[t * 4 + k * (BLOCK * 4)] = z4;

    // This row's 512 tokens, int2 per thread, in registers for all 13 chunks.
    const int2 tk = ((const int2*)(tokens + (size_t)b * SEQ))[t];
    const unsigned int cx = (unsigned int)(tk.x - 1);  // tok==0 -> huge
    const unsigned int cy = (unsigned int)(tk.y - 1);

    float* orow = out + (size_t)b * OUT_COLS;

    LDS_BAR();  // zeros visible

    for (int c = 0; c < NCHUNK; ++c) {
        const unsigned int c0 = (unsigned int)c * CHUNK;

        // Accumulate; atomicAdd returning 0 marks this thread the bin owner.
        const unsigned int rx = cx - c0;
        const unsigned int ry = cy - c0;
        bool wx = false, wy = false;
        if (rx < CHUNK) wx = (atomicAdd(&hist[rx], 1u) == 0u);
        if (ry < CHUNK) wy = (atomicAdd(&hist[ry], 1u) == 0u);

        LDS_BAR();  // all adds for this chunk complete

        // Owners: read final count, one plain dword store (MALL-hit on the
        // line the memset just dirtied), re-zero own bin.
        if (wx) {
            const unsigned int cnt = hist[rx];
            orow[c0 + rx] = (float)cnt;
            hist[rx] = 0u;
        }
        if (wy) {
            const unsigned int cnt = hist[ry];
            orow[c0 + ry] = (float)cnt;
            hist[ry] = 0u;
        }

        LDS_BAR();  // re-zeros visible before next chunk's adds
    }
}

extern "C" void kernel_launch(void* const* d_in, const int* in_sizes, int n_in,
                              void* d_out, int out_size, void* d_ws, size_t ws_size,
                              hipStream_t stream) {
    const int* tokens = (const int*)d_in[0];
    float* out = (float*)d_out;

    // Zero all 205,848,576 output bytes with the rocclr fill kernel (proven
    // 6.7 TB/s store-issue rate on this very buffer). 0x00 == 0.0f bitwise.
    hipMemsetAsync(d_out, 0, (size_t)out_size, stream);

    bow_sparse_kernel<<<dim3(BATCH), dim3(BLOCK), 0, stream>>>(tokens, out);
}